// Round 2
// baseline (712.762 us; speedup 1.0000x reference)
//
#include <hip/hip_runtime.h>

// Window attention: B=4096, L=49, C=256, H=8, D=32
// prep   : weight swizzle (bf16 MFMA B-frag order) + bias table
// prep_x : x -> bf16 A-fragment-swizzled layout in d_ws (big path)
// k1f    : fused qkv + attention, A-frags from global (no xs LDS)
// k1_fb  : previous-round fallback (used when ws_size too small)
// k2     : proj GEMM in-place on d_out

typedef short s8v __attribute__((ext_vector_type(8)));   // 8 bf16 (4 VGPRs)
typedef short s4v __attribute__((ext_vector_type(4)));   // 4 bf16 (8B)
typedef float f4  __attribute__((ext_vector_type(4)));   // MFMA C/D frag

#define MFMA(a,b,c) __builtin_amdgcn_mfma_f32_16x16x32_bf16((a),(b),(c),0,0,0)

__device__ __forceinline__ unsigned short f2bf(float f) {
    unsigned u = __float_as_uint(f);
    u = u + 0x7fffu + ((u >> 16) & 1u);   // round-to-nearest-even
    return (unsigned short)(u >> 16);
}

// ---------------- prep: weight swizzle + bias table ----------------
__global__ void prep(const float* __restrict__ qkv_w, const float* __restrict__ proj_w,
                     const float* __restrict__ rel_bias, const int* __restrict__ rel_idx,
                     unsigned short* __restrict__ wq, unsigned short* __restrict__ wp,
                     float* __restrict__ biasT)
{
    int idx = blockIdx.x * blockDim.x + threadIdx.x;
    int stride = gridDim.x * blockDim.x;
    for (int i = idx; i < 48*8*64*8; i += stride) {
        int j = i & 7, l = (i >> 3) & 63, ks = (i >> 9) & 7, nt = i >> 12;
        int k = ks*32 + (l >> 4)*8 + j;
        int n = nt*16 + (l & 15);
        wq[i] = f2bf(qkv_w[k*768 + n]);
    }
    for (int i = idx; i < 16*8*64*8; i += stride) {
        int j = i & 7, l = (i >> 3) & 63, ks = (i >> 9) & 7, nt = i >> 12;
        int k = ks*32 + (l >> 4)*8 + j;
        int n = nt*16 + (l & 15);
        wp[i] = f2bf(proj_w[k*256 + n]);
    }
    for (int i = idx; i < 8*64*64; i += stride) {
        int q = i & 63, m = (i >> 6) & 63, h = i >> 12;
        float v = -1e30f;
        if (m < 49 && q < 49) v = rel_bias[rel_idx[q*49 + m]*8 + h];
        biasT[i] = v;
    }
}

// ---------------- prep_x: x -> A-frag swizzled bf16 ----------------
// xw element: [b][mt(4)][ks(8)][lane(64)][j(8)] = x[b][mt*16+(l&15)][ks*32+(l>>4)*8+j]
__global__ void prep_x(const float* __restrict__ x, unsigned short* __restrict__ xw)
{
    int idx = blockIdx.x * blockDim.x + threadIdx.x;
    int stride = gridDim.x * blockDim.x;
    const int NQ = 4096 * 64 * 64;             // one float4 per iteration
    for (int i = idx; i < NQ; i += stride) {
        int c4 = i & 63;                        // c = c4*4
        int m  = (i >> 6) & 63;
        int b  = i >> 12;
        int c  = c4 * 4;
        float4 v = make_float4(0.f, 0.f, 0.f, 0.f);
        if (m < 49) v = ((const float4*)(x + (size_t)b*(49*256)))[m*64 + c4];
        int mt = m >> 4, ln = m & 15;
        int ks = c >> 5, g = (c >> 3) & 3, j0 = c & 7;
        size_t dest = (size_t)b*16384 + (((mt*8 + ks)*64) + g*16 + ln)*8 + j0;
        s4v o;
        o[0] = (short)f2bf(v.x); o[1] = (short)f2bf(v.y);
        o[2] = (short)f2bf(v.z); o[3] = (short)f2bf(v.w);
        *(s4v*)&xw[dest] = o;
    }
}

// ---------------- k1f: qkv + attention (A from global) ----------------
__global__ __launch_bounds__(256, 4) void k1f(
    const unsigned short* __restrict__ xw, const float* __restrict__ qkv_b,
    const unsigned short* __restrict__ wq, const float* __restrict__ biasT,
    float* __restrict__ out)
{
    __shared__ __align__(16) unsigned short qsh[2][64][34];   // q*scale [m][d]
    __shared__ __align__(16) unsigned short ksh[2][64][34];   // k       [m][d]
    __shared__ __align__(16) unsigned short vsh[2][32][66];   // v^T     [d][perm(m)]
    // total 25856 B -> ~5 blocks/CU

    const int b    = blockIdx.x;
    const int tid  = threadIdx.x;
    const int w    = tid >> 6;
    const int lane = tid & 63;
    const int ln   = lane & 15;
    const int g    = lane >> 4;

    const unsigned short* xb = xw + (size_t)b * 16384;
    const float scale = 0.17677669529663687f;  // 1/sqrt(32)

    for (int ph = 0; ph < 4; ++ph) {           // head pair: heads 2ph, 2ph+1
        int nts[3];
        #pragma unroll
        for (int t = 0; t < 3; ++t) {
            int qi = 3*w + t;
            nts[t] = (qi >> 2)*16 + 4*ph + (qi & 3);   // which*16 + 4*ph + sub
        }
        f4 acc[4][3];
        #pragma unroll
        for (int mt = 0; mt < 4; ++mt)
            #pragma unroll
            for (int t = 0; t < 3; ++t)
                acc[mt][t] = (f4){0.f, 0.f, 0.f, 0.f};

        #pragma unroll 4
        for (int ks = 0; ks < 8; ++ks) {
            s8v av[4], bv[3];
            #pragma unroll
            for (int mt = 0; mt < 4; ++mt)
                av[mt] = *(const s8v*)&xb[(size_t)((mt*8 + ks)*64 + lane) * 8];
            #pragma unroll
            for (int t = 0; t < 3; ++t)
                bv[t] = *(const s8v*)&wq[(size_t)((nts[t]*8 + ks)*64 + lane) * 8];
            #pragma unroll
            for (int mt = 0; mt < 4; ++mt)
                #pragma unroll
                for (int t = 0; t < 3; ++t)
                    acc[mt][t] = MFMA(av[mt], bv[t], acc[mt][t]);
        }
        // epilogue: +qkv_b, store q/k/v into LDS
        #pragma unroll
        for (int t = 0; t < 3; ++t) {
            int nt = nts[t];
            int which = nt >> 4;                 // 0=q 1=k 2=v
            int hl = ((nt & 15) >> 1) & 1;       // head within pair
            int dh = nt & 1;                     // d half
            float bias = qkv_b[nt*16 + ln];
            int d = dh*16 + ln;
            #pragma unroll
            for (int mt = 0; mt < 4; ++mt) {
                #pragma unroll
                for (int r = 0; r < 4; ++r) {
                    float v = acc[mt][t][r] + bias;
                    int m = mt*16 + g*4 + r;
                    if (which == 0)      qsh[hl][m][d] = f2bf(v * scale);
                    else if (which == 1) ksh[hl][m][d] = f2bf(v);
                    else {
                        int ca = (mt >> 1)*32 + g*8 + (mt & 1)*4 + r;
                        vsh[hl][d][ca] = f2bf(v);
                    }
                }
            }
        }
        __syncthreads();

        // ---- attention: wave -> head hl=w>>1, query tiles {2*(w&1), 2*(w&1)+1} ----
        {
            const int hl  = w >> 1;
            const int hg  = 2*ph + hl;
            const int qt0 = 2*(w & 1);

            f4 st[4][2];
            #pragma unroll
            for (int kt = 0; kt < 4; ++kt) {
                s8v ak = *(const s8v*)&ksh[hl][kt*16 + ln][g*8];
                #pragma unroll
                for (int qq = 0; qq < 2; ++qq) {
                    s8v bq = *(const s8v*)&qsh[hl][(qt0+qq)*16 + ln][g*8];
                    f4 z = (f4){0.f, 0.f, 0.f, 0.f};
                    st[kt][qq] = MFMA(ak, bq, z);
                }
            }

            float pr[2][16];
            #pragma unroll
            for (int qq = 0; qq < 2; ++qq) {
                int q = (qt0+qq)*16 + ln;
                float mx = -3.0e38f;
                #pragma unroll
                for (int kt = 0; kt < 4; ++kt)
                    #pragma unroll
                    for (int r = 0; r < 4; ++r) {
                        int key = kt*16 + g*4 + r;
                        float s = st[kt][qq][r] + biasT[(hg*64 + key)*64 + q];
                        pr[qq][kt*4 + r] = s;
                        mx = fmaxf(mx, s);
                    }
                mx = fmaxf(mx, __shfl_xor(mx, 16));
                mx = fmaxf(mx, __shfl_xor(mx, 32));
                float sum = 0.f;
                #pragma unroll
                for (int i = 0; i < 16; ++i) {
                    float e = __expf(pr[qq][i] - mx);
                    pr[qq][i] = e;
                    sum += e;
                }
                sum += __shfl_xor(sum, 16);
                sum += __shfl_xor(sum, 32);
                float rinv = 1.f / sum;
                #pragma unroll
                for (int i = 0; i < 16; ++i) pr[qq][i] *= rinv;
            }

            #pragma unroll
            for (int qq = 0; qq < 2; ++qq) {
                f4 oacc[2];
                oacc[0] = (f4){0.f, 0.f, 0.f, 0.f};
                oacc[1] = (f4){0.f, 0.f, 0.f, 0.f};
                #pragma unroll
                for (int ksp = 0; ksp < 2; ++ksp) {
                    s8v pa;
                    #pragma unroll
                    for (int j = 0; j < 8; ++j) {
                        int kt = 2*ksp + (j >> 2);
                        int r  = j & 3;
                        pa[j] = (short)f2bf(pr[qq][kt*4 + r]);
                    }
                    #pragma unroll
                    for (int dt = 0; dt < 2; ++dt) {
                        s8v bv2 = *(const s8v*)&vsh[hl][dt*16 + ln][ksp*32 + g*8];
                        oacc[dt] = MFMA(pa, bv2, oacc[dt]);
                    }
                }
                #pragma unroll
                for (int dt = 0; dt < 2; ++dt) {
                    int c = hg*32 + dt*16 + ln;
                    #pragma unroll
                    for (int r = 0; r < 4; ++r) {
                        int q = (qt0+qq)*16 + g*4 + r;
                        if (q < 49)
                            out[((size_t)b*49 + q)*256 + c] = oacc[dt][r];
                    }
                }
            }
        }
        __syncthreads();
    }
}

// ---------------- k1_fb: fallback (x staged in LDS) ----------------
__global__ __launch_bounds__(256, 2) void k1_fb(
    const float* __restrict__ x, const float* __restrict__ qkv_b,
    const unsigned short* __restrict__ wq, const float* __restrict__ biasT,
    float* __restrict__ out)
{
    __shared__ __align__(16) unsigned short xs[64][264];
    __shared__ __align__(16) unsigned short qsh[2][64][40];
    __shared__ __align__(16) unsigned short ksh[2][64][40];
    __shared__ __align__(16) unsigned short vsh[2][32][72];

    const int b    = blockIdx.x;
    const int tid  = threadIdx.x;
    const int w    = tid >> 6;
    const int lane = tid & 63;
    const int ln   = lane & 15;
    const int g    = lane >> 4;

    const float* xb = x + (size_t)b * (49*256);
    for (int i = tid; i < 64*64; i += 256) {
        int r = i >> 6, c4 = i & 63;
        float4 v = make_float4(0.f, 0.f, 0.f, 0.f);
        if (r < 49) v = ((const float4*)xb)[r*64 + c4];
        unsigned short* p = &xs[r][c4*4];
        p[0] = f2bf(v.x); p[1] = f2bf(v.y); p[2] = f2bf(v.z); p[3] = f2bf(v.w);
    }
    __syncthreads();

    const float scale = 0.17677669529663687f;
    for (int ph = 0; ph < 4; ++ph) {
        int nts[3];
        #pragma unroll
        for (int t = 0; t < 3; ++t) {
            int qi = 3*w + t;
            nts[t] = (qi >> 2)*16 + 4*ph + (qi & 3);
        }
        f4 acc[4][3];
        #pragma unroll
        for (int mt = 0; mt < 4; ++mt)
            #pragma unroll
            for (int t = 0; t < 3; ++t)
                acc[mt][t] = (f4){0.f, 0.f, 0.f, 0.f};
        #pragma unroll 2
        for (int ks = 0; ks < 8; ++ks) {
            s8v av[4], bv[3];
            #pragma unroll
            for (int mt = 0; mt < 4; ++mt)
                av[mt] = *(const s8v*)&xs[mt*16 + ln][ks*32 + g*8];
            #pragma unroll
            for (int t = 0; t < 3; ++t)
                bv[t] = *(const s8v*)&wq[(size_t)((nts[t]*8 + ks)*64 + lane) * 8];
            #pragma unroll
            for (int mt = 0; mt < 4; ++mt)
                #pragma unroll
                for (int t = 0; t < 3; ++t)
                    acc[mt][t] = MFMA(av[mt], bv[t], acc[mt][t]);
        }
        #pragma unroll
        for (int t = 0; t < 3; ++t) {
            int nt = nts[t];
            int which = nt >> 4;
            int hl = ((nt & 15) >> 1) & 1;
            int dh = nt & 1;
            float bias = qkv_b[nt*16 + ln];
            int d = dh*16 + ln;
            #pragma unroll
            for (int mt = 0; mt < 4; ++mt)
                #pragma unroll
                for (int r = 0; r < 4; ++r) {
                    float v = acc[mt][t][r] + bias;
                    int m = mt*16 + g*4 + r;
                    if (which == 0)      qsh[hl][m][d] = f2bf(v * scale);
                    else if (which == 1) ksh[hl][m][d] = f2bf(v);
                    else {
                        int ca = (mt >> 1)*32 + g*8 + (mt & 1)*4 + r;
                        vsh[hl][d][ca] = f2bf(v);
                    }
                }
        }
        __syncthreads();
        {
            const int hl  = w >> 1;
            const int hg  = 2*ph + hl;
            const int qt0 = 2*(w & 1);
            f4 st[4][2];
            #pragma unroll
            for (int kt = 0; kt < 4; ++kt) {
                s8v ak = *(const s8v*)&ksh[hl][kt*16 + ln][g*8];
                #pragma unroll
                for (int qq = 0; qq < 2; ++qq) {
                    s8v bq = *(const s8v*)&qsh[hl][(qt0+qq)*16 + ln][g*8];
                    f4 z = (f4){0.f, 0.f, 0.f, 0.f};
                    st[kt][qq] = MFMA(ak, bq, z);
                }
            }
            float pr[2][16];
            #pragma unroll
            for (int qq = 0; qq < 2; ++qq) {
                int q = (qt0+qq)*16 + ln;
                float mx = -3.0e38f;
                #pragma unroll
                for (int kt = 0; kt < 4; ++kt)
                    #pragma unroll
                    for (int r = 0; r < 4; ++r) {
                        int key = kt*16 + g*4 + r;
                        float s = st[kt][qq][r] + biasT[(hg*64 + key)*64 + q];
                        pr[qq][kt*4 + r] = s;
                        mx = fmaxf(mx, s);
                    }
                mx = fmaxf(mx, __shfl_xor(mx, 16));
                mx = fmaxf(mx, __shfl_xor(mx, 32));
                float sum = 0.f;
                #pragma unroll
                for (int i = 0; i < 16; ++i) {
                    float e = __expf(pr[qq][i] - mx);
                    pr[qq][i] = e; sum += e;
                }
                sum += __shfl_xor(sum, 16);
                sum += __shfl_xor(sum, 32);
                float rinv = 1.f / sum;
                #pragma unroll
                for (int i = 0; i < 16; ++i) pr[qq][i] *= rinv;
            }
            #pragma unroll
            for (int qq = 0; qq < 2; ++qq) {
                f4 oacc[2];
                oacc[0] = (f4){0.f,0.f,0.f,0.f};
                oacc[1] = (f4){0.f,0.f,0.f,0.f};
                #pragma unroll
                for (int ksp = 0; ksp < 2; ++ksp) {
                    s8v pa;
                    #pragma unroll
                    for (int j = 0; j < 8; ++j) {
                        int kt = 2*ksp + (j >> 2);
                        pa[j] = (short)f2bf(pr[qq][kt*4 + (j & 3)]);
                    }
                    #pragma unroll
                    for (int dt = 0; dt < 2; ++dt) {
                        s8v bv2 = *(const s8v*)&vsh[hl][dt*16 + ln][ksp*32 + g*8];
                        oacc[dt] = MFMA(pa, bv2, oacc[dt]);
                    }
                }
                #pragma unroll
                for (int dt = 0; dt < 2; ++dt) {
                    int c = hg*32 + dt*16 + ln;
                    #pragma unroll
                    for (int r = 0; r < 4; ++r) {
                        int q = (qt0+qq)*16 + g*4 + r;
                        if (q < 49)
                            out[((size_t)b*49 + q)*256 + c] = oacc[dt][r];
                    }
                }
            }
        }
        __syncthreads();
    }
}

// ---------------- k2: proj GEMM, in-place on d_out ----------------
__global__ __launch_bounds__(256, 4) void k2(
    const unsigned short* __restrict__ wp, const float* __restrict__ proj_b,
    float* __restrict__ out)
{
    __shared__ __align__(16) unsigned short os[64][264];
    const int b    = blockIdx.x;
    const int tid  = threadIdx.x;
    const int w    = tid >> 6;
    const int lane = tid & 63;
    const int ln   = lane & 15;
    const int g    = lane >> 4;

    float* ob = out + (size_t)b * (49*256);

    for (int i = tid; i < 64*64; i += 256) {
        int r = i >> 6, c4 = i & 63;
        float4 v = make_float4(0.f, 0.f, 0.f, 0.f);
        if (r < 49) v = ((const float4*)ob)[r*64 + c4];
        unsigned short* p = &os[r][c4*4];
        p[0] = f2bf(v.x); p[1] = f2bf(v.y); p[2] = f2bf(v.z); p[3] = f2bf(v.w);
    }
    __syncthreads();

    f4 acc[4][4];
    #pragma unroll
    for (int mt = 0; mt < 4; ++mt)
        #pragma unroll
        for (int t = 0; t < 4; ++t)
            acc[mt][t] = (f4){0.f, 0.f, 0.f, 0.f};

    #pragma unroll 2
    for (int ks = 0; ks < 8; ++ks) {
        s8v av[4], bv[4];
        #pragma unroll
        for (int mt = 0; mt < 4; ++mt)
            av[mt] = *(const s8v*)&os[mt*16 + ln][ks*32 + g*8];
        #pragma unroll
        for (int t = 0; t < 4; ++t) {
            int nt = w*4 + t;
            bv[t] = *(const s8v*)&wp[(size_t)((nt*8 + ks)*64 + lane) * 8];
        }
        #pragma unroll
        for (int mt = 0; mt < 4; ++mt)
            #pragma unroll
            for (int t = 0; t < 4; ++t)
                acc[mt][t] = MFMA(av[mt], bv[t], acc[mt][t]);
    }

    #pragma unroll
    for (int t = 0; t < 4; ++t) {
        int n = (w*4 + t)*16 + ln;
        float pb = proj_b[n];
        #pragma unroll
        for (int mt = 0; mt < 4; ++mt)
            #pragma unroll
            for (int r = 0; r < 4; ++r) {
                int q = mt*16 + g*4 + r;
                if (q < 49)
                    ob[q*256 + n] = acc[mt][t][r] + pb;
            }
    }
}

extern "C" void kernel_launch(void* const* d_in, const int* in_sizes, int n_in,
                              void* d_out, int out_size, void* d_ws, size_t ws_size,
                              hipStream_t stream)
{
    (void)n_in; (void)out_size;
    const float* x        = (const float*)d_in[0];
    const int*   rel_idx  = (const int*)  d_in[1];
    const float* qkv_w    = (const float*)d_in[2];
    const float* qkv_b    = (const float*)d_in[3];
    const float* rel_bias = (const float*)d_in[4];
    const float* proj_w   = (const float*)d_in[5];
    const float* proj_b   = (const float*)d_in[6];
    float* out = (float*)d_out;

    const int B = in_sizes[0] / (49*256);

    unsigned short* wq = (unsigned short*)d_ws;                     // 393216 B
    unsigned short* wp = wq + 48*8*64*8;                            // 131072 B
    float* biasT = (float*)((char*)d_ws + 524288);                  // 131072 B
    unsigned short* xw = (unsigned short*)((char*)d_ws + 655360);   // 134217728 B

    const size_t NEED = 655360 + (size_t)B * 16384 * 2;

    prep<<<256, 256, 0, stream>>>(qkv_w, proj_w, rel_bias, rel_idx, wq, wp, biasT);
    if (ws_size >= NEED) {
        prep_x<<<4096, 256, 0, stream>>>(x, xw);
        k1f<<<B, 256, 0, stream>>>(xw, qkv_b, wq, biasT, out);
    } else {
        k1_fb<<<B, 256, 0, stream>>>(x, qkv_b, wq, biasT, out);
    }
    k2<<<B, 256, 0, stream>>>(wp, proj_b, out);
}

// Round 3
// 447.539 us; speedup vs baseline: 1.5926x; 1.5926x over previous
//
#include <hip/hip_runtime.h>

// Window attention: B=4096, L=49, C=256, H=8, D=32
// prep : weight swizzle (bf16 MFMA frag order) + bias table (unchanged layouts)
// kall : fully fused qkv GEMM + attention + proj, one block per window.
//
// Core trick: Q,K computed TRANSPOSED (C' = W^T x^T -> lane holds [m=lane][d=reg]),
// V computed normal (lane holds [m=reg][d=lane]). With the symmetric k-remap
// kappa(g,j) = 16*(j>>2) + 4*g + (j&3) applied to BOTH operands of QK^T and PV,
// every attention MFMA operand is an in-lane repack of GEMM accumulators:
// q/k/v never touch LDS. Only x-frags (32KB) and O (33.8KB) live in LDS.

typedef short s8v __attribute__((ext_vector_type(8)));   // 8 bf16 (4 VGPRs)
typedef short s4v __attribute__((ext_vector_type(4)));   // 4 bf16 (8B)
typedef float f4  __attribute__((ext_vector_type(4)));   // MFMA C/D frag

#define MFMA(a,b,c) __builtin_amdgcn_mfma_f32_16x16x32_bf16((a),(b),(c),0,0,0)

__device__ __forceinline__ unsigned short f2bf(float f) {
    unsigned u = __float_as_uint(f);
    u = u + 0x7fffu + ((u >> 16) & 1u);   // round-to-nearest-even
    return (unsigned short)(u >> 16);
}

// ---------------- prep: weight swizzle + bias table ----------------
// wq layout: [nt=48][ks=8][lane=64][j=8]; element = qkv_w[ks*32+(lane>>4)*8+j][nt*16+(lane&15)]
// (this layout serves BOTH as B-frag for normal GEMM and A-frag for transposed GEMM)
// wp: same with nt=16 over proj_w
// biasT: [h=8][key=64][query=64] fp32, -1e30 for key>=49 or query>=49
__global__ void prep(const float* __restrict__ qkv_w, const float* __restrict__ proj_w,
                     const float* __restrict__ rel_bias, const int* __restrict__ rel_idx,
                     unsigned short* __restrict__ wq, unsigned short* __restrict__ wp,
                     float* __restrict__ biasT)
{
    int idx = blockIdx.x * blockDim.x + threadIdx.x;
    int stride = gridDim.x * blockDim.x;
    for (int i = idx; i < 48*8*64*8; i += stride) {
        int j = i & 7, l = (i >> 3) & 63, ks = (i >> 9) & 7, nt = i >> 12;
        int k = ks*32 + (l >> 4)*8 + j;
        int n = nt*16 + (l & 15);
        wq[i] = f2bf(qkv_w[k*768 + n]);
    }
    for (int i = idx; i < 16*8*64*8; i += stride) {
        int j = i & 7, l = (i >> 3) & 63, ks = (i >> 9) & 7, nt = i >> 12;
        int k = ks*32 + (l >> 4)*8 + j;
        int n = nt*16 + (l & 15);
        wp[i] = f2bf(proj_w[k*256 + n]);
    }
    for (int i = idx; i < 8*64*64; i += stride) {
        int q = i & 63, m = (i >> 6) & 63, h = i >> 12;
        float v = -1e30f;
        if (m < 49 && q < 49) v = rel_bias[rel_idx[q*49 + m]*8 + h];
        biasT[i] = v;
    }
}

// ---------------- kall: fused qkv + attention + proj ----------------
__global__ __launch_bounds__(256, 2) void kall(
    const float* __restrict__ x, const float* __restrict__ qkv_b,
    const unsigned short* __restrict__ wq, const float* __restrict__ biasT,
    const unsigned short* __restrict__ wp, const float* __restrict__ proj_b,
    float* __restrict__ out)
{
    __shared__ __align__(16) unsigned short xs[4][8][64][8];   // x frags, 32768 B
    __shared__ __align__(16) unsigned short osd[64][264];      // O bf16 row-major, 33792 B

    const int b    = blockIdx.x;
    const int tid  = threadIdx.x;
    const int w    = tid >> 6;
    const int lane = tid & 63;
    const int ln   = lane & 15;
    const int g    = lane >> 4;

    // ---- stage x -> frag-layout bf16 LDS ----
    const float* xb = x + (size_t)b * (49*256);
    for (int i = tid; i < 4096; i += 256) {
        int r = i >> 6, c4 = i & 63;
        float4 v = make_float4(0.f, 0.f, 0.f, 0.f);
        if (r < 49) v = ((const float4*)xb)[r*64 + c4];
        s4v o;
        o[0] = (short)f2bf(v.x); o[1] = (short)f2bf(v.y);
        o[2] = (short)f2bf(v.z); o[3] = (short)f2bf(v.w);
        int mt = r >> 4, lnr = r & 15;
        int c  = c4 * 4;
        int ks = c >> 5, gg = (c >> 3) & 3, j0 = c & 7;
        *(s4v*)&xs[mt][ks][gg*16 + lnr][j0] = o;
    }
    __syncthreads();

    const float scale = 0.17677669529663687f;  // 1/sqrt(32)

    for (int p = 0; p < 2; ++p) {
        const int h = 2*w + p;                 // this wave's head for this pass

        // ---- QKV GEMM ----
        // qa/ka (transposed): qa[dh][mt][r] = Q[m=mt*16+ln][d=dh*16+g*4+r]
        // va (normal):        va[mt][dh][r] = V[m=mt*16+g*4+r][d=dh*16+ln]
        f4 qa[2][4], ka[2][4], va[4][2];
        #pragma unroll
        for (int dh = 0; dh < 2; ++dh)
            #pragma unroll
            for (int mt = 0; mt < 4; ++mt) {
                qa[dh][mt] = (f4){0.f,0.f,0.f,0.f};
                ka[dh][mt] = (f4){0.f,0.f,0.f,0.f};
                va[mt][dh] = (f4){0.f,0.f,0.f,0.f};
            }

        #pragma unroll
        for (int ks = 0; ks < 8; ++ks) {
            s8v xf[4];
            #pragma unroll
            for (int mt = 0; mt < 4; ++mt)
                xf[mt] = *(const s8v*)&xs[mt][ks][lane][0];
            s8v wfq[2], wfk[2], wfv[2];
            #pragma unroll
            for (int dh = 0; dh < 2; ++dh) {
                wfq[dh] = *(const s8v*)&wq[(size_t)((( 2*h+dh)*8 + ks)*64 + lane) * 8];
                wfk[dh] = *(const s8v*)&wq[(size_t)(((16+2*h+dh)*8 + ks)*64 + lane) * 8];
                wfv[dh] = *(const s8v*)&wq[(size_t)(((32+2*h+dh)*8 + ks)*64 + lane) * 8];
            }
            #pragma unroll
            for (int dh = 0; dh < 2; ++dh)
                #pragma unroll
                for (int mt = 0; mt < 4; ++mt) {
                    qa[dh][mt] = MFMA(wfq[dh], xf[mt], qa[dh][mt]);   // A=W', B=x' (transposed)
                    ka[dh][mt] = MFMA(wfk[dh], xf[mt], ka[dh][mt]);
                    va[mt][dh] = MFMA(xf[mt], wfv[dh], va[mt][dh]);   // A=x, B=W (normal)
                }
        }

        // ---- biases ----
        float4 bq[2], bk[2]; float bv[2];
        #pragma unroll
        for (int dh = 0; dh < 2; ++dh) {
            bq[dh] = *(const float4*)&qkv_b[       h*32 + dh*16 + g*4];
            bk[dh] = *(const float4*)&qkv_b[256 +  h*32 + dh*16 + g*4];
            bv[dh] = qkv_b[512 + h*32 + dh*16 + ln];
        }

        // ---- in-lane repack to bf16 frags (kappa mapping) ----
        // kf[kt][j] = K[kt*16+ln][kappa(g,j)],  qf[qt][j] = Q[qt*16+ln][kappa(g,j)]
        // vf[ksp][dh][j] = V[ksp*32+kappa(g,j)][dh*16+ln]
        s8v qf[4], kf[4], vf[2][2];
        #pragma unroll
        for (int t = 0; t < 4; ++t)
            #pragma unroll
            for (int j = 0; j < 8; ++j) {
                int dh = j >> 2, r = j & 3;
                qf[t][j] = (short)f2bf((qa[dh][t][r] + ((const float*)&bq[dh])[r]) * scale);
                kf[t][j] = (short)f2bf( ka[dh][t][r] + ((const float*)&bk[dh])[r]);
            }
        #pragma unroll
        for (int ksp = 0; ksp < 2; ++ksp)
            #pragma unroll
            for (int dh = 0; dh < 2; ++dh)
                #pragma unroll
                for (int j = 0; j < 8; ++j)
                    vf[ksp][dh][j] = (short)f2bf(va[2*ksp + (j>>2)][dh][j & 3] + bv[dh]);

        // ---- attention (per query tile) ----
        f4 oacc[4][2];
        #pragma unroll
        for (int qt = 0; qt < 4; ++qt)
            #pragma unroll
            for (int dh = 0; dh < 2; ++dh)
                oacc[qt][dh] = (f4){0.f,0.f,0.f,0.f};

        #pragma unroll
        for (int qt = 0; qt < 4; ++qt) {
            // S^T tile: st[kt][r] = S^T[key=kt*16+g*4+r][q=qt*16+ln]
            f4 st[4];
            #pragma unroll
            for (int kt = 0; kt < 4; ++kt) {
                f4 z = (f4){0.f,0.f,0.f,0.f};
                st[kt] = MFMA(kf[kt], qf[qt], z);
            }
            float pr[16];
            float mx = -3.0e38f;
            #pragma unroll
            for (int kt = 0; kt < 4; ++kt)
                #pragma unroll
                for (int r = 0; r < 4; ++r) {
                    float s = st[kt][r] + biasT[(h*64 + kt*16 + g*4 + r)*64 + qt*16 + ln];
                    pr[kt*4 + r] = s;
                    mx = fmaxf(mx, s);
                }
            mx = fmaxf(mx, __shfl_xor(mx, 16));
            mx = fmaxf(mx, __shfl_xor(mx, 32));
            float sum = 0.f;
            #pragma unroll
            for (int i = 0; i < 16; ++i) {
                float e = __expf(pr[i] - mx);
                pr[i] = e;
                sum += e;
            }
            sum += __shfl_xor(sum, 16);
            sum += __shfl_xor(sum, 32);
            float rinv = 1.f / sum;

            // P A-frag: pa[ksp][j] = P[q=qt*16+ln][ksp*32+kappa(g,j)]
            s8v pa[2];
            #pragma unroll
            for (int ksp = 0; ksp < 2; ++ksp)
                #pragma unroll
                for (int j = 0; j < 8; ++j)
                    pa[ksp][j] = (short)f2bf(pr[8*ksp + 4*(j>>2) + (j&3)] * rinv);

            #pragma unroll
            for (int ksp = 0; ksp < 2; ++ksp)
                #pragma unroll
                for (int dh = 0; dh < 2; ++dh)
                    oacc[qt][dh] = MFMA(pa[ksp], vf[ksp][dh], oacc[qt][dh]);
        }

        // ---- O -> LDS (row-major bf16; columns disjoint per wave) ----
        #pragma unroll
        for (int qt = 0; qt < 4; ++qt)
            #pragma unroll
            for (int dh = 0; dh < 2; ++dh)
                #pragma unroll
                for (int r = 0; r < 4; ++r)
                    osd[qt*16 + g*4 + r][h*32 + dh*16 + ln] = f2bf(oacc[qt][dh][r]);
    }
    __syncthreads();

    // ---- proj GEMM: out = O @ Wp + b ----
    f4 acc[4][4];
    #pragma unroll
    for (int mt = 0; mt < 4; ++mt)
        #pragma unroll
        for (int t = 0; t < 4; ++t)
            acc[mt][t] = (f4){0.f,0.f,0.f,0.f};

    #pragma unroll
    for (int ks = 0; ks < 8; ++ks) {
        s8v av[4], bw[4];
        #pragma unroll
        for (int mt = 0; mt < 4; ++mt)
            av[mt] = *(const s8v*)&osd[mt*16 + ln][ks*32 + g*8];
        #pragma unroll
        for (int t = 0; t < 4; ++t) {
            int nt = w*4 + t;
            bw[t] = *(const s8v*)&wp[(size_t)((nt*8 + ks)*64 + lane) * 8];
        }
        #pragma unroll
        for (int mt = 0; mt < 4; ++mt)
            #pragma unroll
            for (int t = 0; t < 4; ++t)
                acc[mt][t] = MFMA(av[mt], bw[t], acc[mt][t]);
    }

    float* ob = out + (size_t)b * (49*256);
    #pragma unroll
    for (int t = 0; t < 4; ++t) {
        int n = (w*4 + t)*16 + ln;
        float pb = proj_b[n];
        #pragma unroll
        for (int mt = 0; mt < 4; ++mt)
            #pragma unroll
            for (int r = 0; r < 4; ++r) {
                int q = mt*16 + g*4 + r;
                if (q < 49)
                    ob[q*256 + n] = acc[mt][t][r] + pb;
            }
    }
}

extern "C" void kernel_launch(void* const* d_in, const int* in_sizes, int n_in,
                              void* d_out, int out_size, void* d_ws, size_t ws_size,
                              hipStream_t stream)
{
    (void)n_in; (void)out_size; (void)ws_size;
    const float* x        = (const float*)d_in[0];
    const int*   rel_idx  = (const int*)  d_in[1];
    const float* qkv_w    = (const float*)d_in[2];
    const float* qkv_b    = (const float*)d_in[3];
    const float* rel_bias = (const float*)d_in[4];
    const float* proj_w   = (const float*)d_in[5];
    const float* proj_b   = (const float*)d_in[6];
    float* out = (float*)d_out;

    const int B = in_sizes[0] / (49*256);

    unsigned short* wq = (unsigned short*)d_ws;                     // 393216 B
    unsigned short* wp = wq + 48*8*64*8;                            // 131072 B
    float* biasT = (float*)((char*)d_ws + 524288);                  // 131072 B

    prep<<<256, 256, 0, stream>>>(qkv_w, proj_w, rel_bias, rel_idx, wq, wp, biasT);
    kall<<<B, 256, 0, stream>>>(x, qkv_b, wq, biasT, wp, proj_b, out);
}